// Round 2
// baseline (1609.479 us; speedup 1.0000x reference)
//
#include <hip/hip_runtime.h>
#include <hip/hip_bf16.h>
#include <cstdio>

typedef __bf16 bf16;
typedef __bf16 bf16x8 __attribute__((ext_vector_type(8)));
typedef __bf16 bf16x4 __attribute__((ext_vector_type(4)));
typedef float f32x4 __attribute__((ext_vector_type(4)));

__device__ __forceinline__ float sigmoidf_(float x) { return 1.f / (1.f + __expf(-x)); }
__device__ __forceinline__ float tanhf_(float x)    { return 1.f - 2.f / (__expf(2.f * x) + 1.f); }

// async global->LDS, 16 bytes per lane. LDS dest must be wave-uniform base +
// lane*16 (m104/m108) — all call sites index LDS with (tid-contiguous)*16B.
__device__ __forceinline__ void gld_lds16(const bf16* g, bf16* l) {
    __builtin_amdgcn_global_load_lds(
        (const __attribute__((address_space(1))) void*)g,
        (__attribute__((address_space(3))) void*)l, 16, 0, 0);
}

// ---------------------------------------------------------------------------
// m97-structure bf16 GEMM: C[M,N] = A[M,K] * B[N,K]^T + bias[N]
// Operands bf16, K-major. LDS tiles unpadded [B*][32] row-major, staged with
// global_load_lds dwordx4. Block 256 = 4 waves (2x2), wave tile (BM/2)x(BN/2).
// ---------------------------------------------------------------------------
template<int BM, int BN, bool OUTBF16, bool NBOUND>
__global__ __launch_bounds__(256)
void gemm_lds_k(const bf16* __restrict__ A, const bf16* __restrict__ B,
                void* __restrict__ Cv, const float* __restrict__ bias,
                int K, int lda, int ldb, int ldc, int Nlim)
{
    constexpr int TM = BM / 32;
    constexpr int TN = BN / 32;

    __shared__ __align__(16) bf16 As[BM * 32];
    __shared__ __align__(16) bf16 Bs[BN * 32];

    const int tid  = threadIdx.x;
    const int wave = tid >> 6;
    const int lane = tid & 63;
    const int lrow = lane & 15;
    const int q    = lane >> 4;

    const int rowbase = blockIdx.y * BM;
    const int colbase = blockIdx.x * BN;
    const int wr = (wave >> 1) * (BM / 2);
    const int wc = (wave & 1) * (BN / 2);

    f32x4 acc[TM][TN] = {};

    for (int kk = 0; kk < K; kk += 32) {
        __syncthreads();
        #pragma unroll
        for (int i = 0; i < BM / 64; ++i) {
            int c  = tid + i * 256;          // chunk id; LDS byte off = c*16
            int r  = c >> 2;
            int kc = (c & 3) * 8;
            gld_lds16(A + (size_t)(rowbase + r) * lda + kk + kc, &As[c * 8]);
        }
        #pragma unroll
        for (int i = 0; i < BN / 64; ++i) {
            int c  = tid + i * 256;
            int r  = c >> 2;
            int kc = (c & 3) * 8;
            gld_lds16(B + (size_t)(colbase + r) * ldb + kk + kc, &Bs[c * 8]);
        }
        __syncthreads();

        bf16x8 afr[TM], bfr[TN];
        #pragma unroll
        for (int m = 0; m < TM; ++m)
            afr[m] = *(const bf16x8*)&As[(wr + m * 16 + lrow) * 32 + q * 8];
        #pragma unroll
        for (int n = 0; n < TN; ++n)
            bfr[n] = *(const bf16x8*)&Bs[(wc + n * 16 + lrow) * 32 + q * 8];
        #pragma unroll
        for (int m = 0; m < TM; ++m)
            #pragma unroll
            for (int n = 0; n < TN; ++n)
                acc[m][n] = __builtin_amdgcn_mfma_f32_16x16x32_bf16(
                                afr[m], bfr[n], acc[m][n], 0, 0, 0);
    }

    #pragma unroll
    for (int m = 0; m < TM; ++m) {
        #pragma unroll
        for (int n = 0; n < TN; ++n) {
            int gr0 = rowbase + wr + m * 16 + q * 4;
            int gc  = colbase + wc + n * 16 + lrow;
            bool cok = (!NBOUND) || (gc < Nlim);
            float bv = cok ? bias[gc] : 0.f;
            #pragma unroll
            for (int rix = 0; rix < 4; ++rix) {
                if (cok) {
                    float v = acc[m][n][rix] + bv;
                    size_t o = (size_t)(gr0 + rix) * ldc + gc;
                    if (OUTBF16) ((bf16*)Cv)[o] = (bf16)v;
                    else         ((float*)Cv)[o] = v;
                }
            }
        }
    }
}

// ---------------------------------------------------------------------------
// Fallback big GEMM (operands fp32, cast during staging). Only used if ws is
// too small for precast buffers. LDK=40-padded LDS, VGPR staging.
// ---------------------------------------------------------------------------
template<int BM, int BN>
__global__ __launch_bounds__(256)
void gemm_cast_k(const float* __restrict__ Av, const float* __restrict__ Bv,
                 bf16* __restrict__ Cv, const float* __restrict__ bias,
                 int K, int Klim, int lda, int ldb, int ldc)
{
    constexpr int TM = BM / 32;
    constexpr int TN = BN / 32;
    constexpr int LDK = 40;

    __shared__ __align__(16) bf16 As[BM * LDK];
    __shared__ __align__(16) bf16 Bs[BN * LDK];

    const int tid  = threadIdx.x;
    const int wave = tid >> 6;
    const int lane = tid & 63;
    const int lrow = lane & 15;
    const int q    = lane >> 4;

    const int rowbase = blockIdx.y * BM;
    const int colbase = blockIdx.x * BN;
    const int wr = (wave >> 1) * (BM / 2);
    const int wc = (wave & 1) * (BN / 2);

    f32x4 acc[TM][TN] = {};

    for (int kk = 0; kk < K; kk += 32) {
        __syncthreads();
        #pragma unroll
        for (int i = 0; i < BM / 64; ++i) {
            int c = tid + i * 256;
            int r = c >> 2, kc = (c & 3) * 8, kg = kk + kc;
            const float* src = Av + (size_t)(rowbase + r) * lda + kg;
            bf16x8 v;
            if (kg + 8 <= Klim) {
                float4 f0 = *(const float4*)(src);
                float4 f1 = *(const float4*)(src + 4);
                v[0]=(bf16)f0.x; v[1]=(bf16)f0.y; v[2]=(bf16)f0.z; v[3]=(bf16)f0.w;
                v[4]=(bf16)f1.x; v[5]=(bf16)f1.y; v[6]=(bf16)f1.z; v[7]=(bf16)f1.w;
            } else {
                #pragma unroll
                for (int e = 0; e < 8; ++e) v[e] = (kg + e < Klim) ? (bf16)src[e] : (bf16)0.f;
            }
            *(bf16x8*)&As[r * LDK + kc] = v;
        }
        #pragma unroll
        for (int i = 0; i < BN / 64; ++i) {
            int c = tid + i * 256;
            int r = c >> 2, kc = (c & 3) * 8, kg = kk + kc;
            const float* src = Bv + (size_t)(colbase + r) * ldb + kg;
            bf16x8 v;
            if (kg + 8 <= Klim) {
                float4 f0 = *(const float4*)(src);
                float4 f1 = *(const float4*)(src + 4);
                v[0]=(bf16)f0.x; v[1]=(bf16)f0.y; v[2]=(bf16)f0.z; v[3]=(bf16)f0.w;
                v[4]=(bf16)f1.x; v[5]=(bf16)f1.y; v[6]=(bf16)f1.z; v[7]=(bf16)f1.w;
            } else {
                #pragma unroll
                for (int e = 0; e < 8; ++e) v[e] = (kg + e < Klim) ? (bf16)src[e] : (bf16)0.f;
            }
            *(bf16x8*)&Bs[r * LDK + kc] = v;
        }
        __syncthreads();

        bf16x8 afr[TM], bfr[TN];
        #pragma unroll
        for (int m = 0; m < TM; ++m)
            afr[m] = *(const bf16x8*)&As[(wr + m * 16 + lrow) * LDK + q * 8];
        #pragma unroll
        for (int n = 0; n < TN; ++n)
            bfr[n] = *(const bf16x8*)&Bs[(wc + n * 16 + lrow) * LDK + q * 8];
        #pragma unroll
        for (int m = 0; m < TM; ++m)
            #pragma unroll
            for (int n = 0; n < TN; ++n)
                acc[m][n] = __builtin_amdgcn_mfma_f32_16x16x32_bf16(
                                afr[m], bfr[n], acc[m][n], 0, 0, 0);
    }

    #pragma unroll
    for (int m = 0; m < TM; ++m) {
        #pragma unroll
        for (int n = 0; n < TN; ++n) {
            int gr0 = rowbase + wr + m * 16 + q * 4;
            int gc  = colbase + wc + n * 16 + lrow;
            float bv = bias[gc];
            #pragma unroll
            for (int rix = 0; rix < 4; ++rix)
                Cv[(size_t)(gr0 + rix) * ldc + gc] = (bf16)(acc[m][n][rix] + bv);
        }
    }
}

// ---------------------------------------------------------------------------
// Fused recurrent step: for each (b,h) compute all 5 state-projections via
// MFMA (K=1024) then apply gates in-register; write h_t (bf16) and c (fp32).
// Block tile: 64 batch x 16 h x 5 gates. 4 waves split batch (16 rows each).
// Grid: (H/16=64, B/64=4) = 256 blocks = 1 per CU.
// ---------------------------------------------------------------------------
__global__ __launch_bounds__(256)
void step_k(const bf16* __restrict__ hprev,    // [256][1024]
            const bf16* __restrict__ wsb,      // [5120][1024]
            const bf16* __restrict__ pi_t,     // [256][6144] (b_in included)
            const float* __restrict__ b_state, // [5120]
            float* __restrict__ cst,           // [256][1024]
            const float* __restrict__ dmask,   // [256][1024]
            bf16* __restrict__ hnext)          // [256][1024]
{
    constexpr int BK = 64, LDP = 72;           // 72: +8 pad, rows spread banks
    __shared__ __align__(16) bf16 Ahs[64 * LDP];
    __shared__ __align__(16) bf16 Bws[80 * LDP];

    const int tid  = threadIdx.x;
    const int wv   = tid >> 6;
    const int lane = tid & 63;
    const int lrow = lane & 15;
    const int q    = lane >> 4;
    const int hbase = blockIdx.x * 16;
    const int bbase = blockIdx.y * 64;

    f32x4 acc[5] = {};

    for (int kk = 0; kk < 1024; kk += BK) {
        __syncthreads();
        // stage A: 64 batch rows x 64 k  (512 chunks of 8 bf16)
        #pragma unroll
        for (int i = 0; i < 2; ++i) {
            int c = tid + i * 256;
            int r = c >> 3, kc = (c & 7) * 8;
            *(bf16x8*)&Ahs[r * LDP + kc] =
                *(const bf16x8*)&hprev[(size_t)(bbase + r) * 1024 + kk + kc];
        }
        // stage B: 5 gates x 16 h rows x 64 k  (640 chunks)
        #pragma unroll
        for (int i = 0; i < 3; ++i) {
            int c = tid + i * 256;
            if (c < 640) {
                int r = c >> 3, kc = (c & 7) * 8;
                int g = r >> 4, hh = r & 15;
                *(bf16x8*)&Bws[r * LDP + kc] =
                    *(const bf16x8*)&wsb[(size_t)(g * 1024 + hbase + hh) * 1024 + kk + kc];
            }
        }
        __syncthreads();

        #pragma unroll
        for (int ks = 0; ks < 2; ++ks) {
            bf16x8 af = *(const bf16x8*)&Ahs[(wv * 16 + lrow) * LDP + ks * 32 + q * 8];
            #pragma unroll
            for (int g = 0; g < 5; ++g) {
                bf16x8 bf = *(const bf16x8*)&Bws[(g * 16 + lrow) * LDP + ks * 32 + q * 8];
                acc[g] = __builtin_amdgcn_mfma_f32_16x16x32_bf16(af, bf, acc[g], 0, 0, 0);
            }
        }
    }

    // gates in-register: lane's col = lrow -> h, rows q*4+rix -> batch
    const int hh = hbase + lrow;
    const float bs0 = b_state[hh],        bs1 = b_state[1024 + hh];
    const float bs2 = b_state[2048 + hh], bs3 = b_state[3072 + hh];
    const float bs4 = b_state[4096 + hh];
    #pragma unroll
    for (int rix = 0; rix < 4; ++rix) {
        int b = bbase + wv * 16 + q * 4 + rix;
        const bf16* pib = pi_t + (size_t)b * 6144 + hh;
        float p0 = acc[0][rix] + bs0 + (float)pib[0];
        float p1 = acc[1][rix] + bs1 + (float)pib[1024];
        float p2 = acc[2][rix] + bs2 + (float)pib[2048];
        float p3 = acc[3][rix] + bs3 + (float)pib[3072];
        float p4 = acc[4][rix] + bs4 + (float)pib[4096];
        float p5 = (float)pib[5120];

        float ig = sigmoidf_(p0);
        float fg = sigmoidf_(p1);
        float mi = tanhf_(p2);
        float og = sigmoidf_(p3);
        float hw = sigmoidf_(p4);

        int j = b * 1024 + hh;
        float mem = ig * mi + fg * cst[j];
        cst[j] = mem;
        float out = og * tanhf_(mem);
        out = hw * out + (1.f - hw) * p5;
        out *= dmask[j];
        hnext[j] = (bf16)out;
    }
}

// ---------------------------------------------------------------------------
// casts / init
// ---------------------------------------------------------------------------
__global__ void cast_f2b4_k(const float* __restrict__ src, bf16* __restrict__ dst, int n4) {
    int i = blockIdx.x * 256 + threadIdx.x;
    if (i < n4) {
        float4 f = *(const float4*)(src + i * 4);
        bf16x4 v; v[0]=(bf16)f.x; v[1]=(bf16)f.y; v[2]=(bf16)f.z; v[3]=(bf16)f.w;
        *(bf16x4*)(dst + i * 4) = v;
    }
}

// W_out [C,H] -> bf16 [192,H], rows >= C zero-filled
__global__ void cast_wout_k(const float* __restrict__ src, bf16* __restrict__ dst, int Crows) {
    int i = blockIdx.x * 256 + threadIdx.x;    // over 192*1024
    int r = i >> 10;
    dst[i] = (r < Crows) ? (bf16)src[i] : (bf16)0.f;
}

// row-wise cast with K padding (vec4): src [rows, klim] f32 -> dst [rows, kp] bf16
__global__ void cast_pad4_k(const float* __restrict__ src, bf16* __restrict__ dst,
                            int klim, int kp) {
    int r = blockIdx.x;
    const float* s = src + (size_t)r * klim;
    bf16* d = dst + (size_t)r * kp;
    int nk4 = kp >> 2, lim4 = klim >> 2;       // klim % 4 == 0 here
    for (int c = threadIdx.x; c < nk4; c += 256) {
        bf16x4 v;
        if (c < lim4) {
            float4 f = *(const float4*)(s + c * 4);
            v[0]=(bf16)f.x; v[1]=(bf16)f.y; v[2]=(bf16)f.z; v[3]=(bf16)f.w;
        } else {
            v[0]=v[1]=v[2]=v[3]=(bf16)0.f;
        }
        *(bf16x4*)(d + c * 4) = v;
    }
}

__global__ void init_state_k(const float* __restrict__ c0, const float* __restrict__ h0,
                             float* __restrict__ cst, bf16* __restrict__ hs0) {
    int i = blockIdx.x * 256 + threadIdx.x;
    cst[i] = c0[i];
    hs0[i] = (bf16)h0[i];
}

// ---------------------------------------------------------------------------
extern "C" void kernel_launch(void* const* d_in, const int* in_sizes, int n_in,
                              void* d_out, int out_size, void* d_ws, size_t ws_size,
                              hipStream_t stream)
{
    const float* x       = (const float*)d_in[0];
    const float* h0      = (const float*)d_in[1];
    const float* c0      = (const float*)d_in[2];
    const float* dmask   = (const float*)d_in[3];
    const float* W_in    = (const float*)d_in[4];
    const float* b_in    = (const float*)d_in[5];
    const float* W_state = (const float*)d_in[6];
    const float* b_state = (const float*)d_in[7];
    const float* W_out   = (const float*)d_in[8];
    const float* b_out   = (const float*)d_in[9];

    constexpr int T = 32, B = 256, DIN = 4196, H = 1024, C = 151;
    constexpr int M  = T * B;       // 8192
    constexpr int KP = 4224;        // DIN padded to multiple of 32
    constexpr int N6 = 6 * H;       // 6144
    constexpr int N5 = 5 * H;       // 5120

    size_t off = 0;
    auto carve = [&](size_t bytes) -> void* {
        void* p = (char*)d_ws + off;
        off += (bytes + 255) & ~(size_t)255;
        return p;
    };
    bf16*  pi  = (bf16*) carve((size_t)M * N6 * 2);          // 100.7 MB
    bf16*  wsb = (bf16*) carve((size_t)N5 * H * 2);          //  10.5 MB
    bf16*  wob = (bf16*) carve((size_t)192 * H * 2);         //   0.4 MB
    bf16*  hs  = (bf16*) carve((size_t)(T + 1) * B * H * 2); //  17.3 MB
    float* cst = (float*)carve((size_t)B * H * 4);           //   1.0 MB
    size_t base_need = off;

    bf16 *xb = nullptr, *wb = nullptr;
    bool precast = (ws_size >= base_need + (size_t)M * KP * 2 + (size_t)N6 * KP * 2 + 1024);
    if (precast) {
        xb = (bf16*)carve((size_t)M * KP * 2);               // 69.2 MB
        wb = (bf16*)carve((size_t)N6 * KP * 2);              // 51.9 MB
    }
    if (ws_size < base_need) {
        fprintf(stderr, "kernel_launch: ws too small (%zu < %zu)\n", ws_size, base_need);
        return;
    }

    // ---- init / weight casts ----
    hipLaunchKernelGGL(cast_f2b4_k, dim3((N5 * H / 4 + 255) / 256), dim3(256), 0, stream,
                       W_state, wsb, N5 * H / 4);
    hipLaunchKernelGGL(cast_wout_k, dim3(192 * H / 256), dim3(256), 0, stream, W_out, wob, C);
    hipLaunchKernelGGL(init_state_k, dim3(B * H / 256), dim3(256), 0, stream, c0, h0, cst, hs);

    // ---- big input-projection GEMM: pi = bf16(X @ W_in^T + b_in) ----
    if (precast) {
        hipLaunchKernelGGL(cast_pad4_k, dim3(M),  dim3(256), 0, stream, x,    xb, DIN, KP);
        hipLaunchKernelGGL(cast_pad4_k, dim3(N6), dim3(256), 0, stream, W_in, wb, DIN, KP);
        hipLaunchKernelGGL((gemm_lds_k<128, 128, true, false>),
                           dim3(N6 / 128, M / 128), dim3(256), 0, stream,
                           xb, wb, pi, b_in, KP, KP, KP, N6, N6);
    } else {
        hipLaunchKernelGGL((gemm_cast_k<128, 128>),
                           dim3(N6 / 128, M / 128), dim3(256), 0, stream,
                           x, W_in, pi, b_in, KP, DIN, DIN, DIN, N6);
    }

    // ---- recurrence: 32 fused step kernels ----
    for (int t = 0; t < T; ++t) {
        hipLaunchKernelGGL(step_k, dim3(H / 16, B / 64), dim3(256), 0, stream,
                           hs + (size_t)t * B * H, wsb,
                           pi + (size_t)t * B * N6, b_state,
                           cst, dmask,
                           hs + (size_t)(t + 1) * B * H);
    }

    // ---- output projection: logits = hs @ W_out^T + b_out ----
    hipLaunchKernelGGL((gemm_lds_k<128, 64, false, true>),
                       dim3(192 / 64, M / 128), dim3(256), 0, stream,
                       hs + (size_t)B * H, wob, (float*)d_out, b_out,
                       H, H, H, C, C);
}